// Round 6
// baseline (307.276 us; speedup 1.0000x reference)
//
#include <hip/hip_runtime.h>
#include <hip/hip_bf16.h>
#include <stdint.h>

// Problem dims (fixed by setup_inputs)
#define M_TOTAL 2048     // B (feats rows)
#define N_TOTAL 16384    // Bs*TOPK (support rows)
#define K_TOTAL 2048     // C
#define NPARTS  256      // 128 n-tiles * 2 n-waves

// Uniform MX scale: stored_fp8 = value * 2^9, HW dequant scale = 2^-9 per operand.
// e8m0 byte = 127 - 9 = 118 = 0x76. Uniform bytes -> immune to scale-lane layout.
#define SCALE_E8M0 0x76767676
#define SCALE_F 512.0f

typedef __attribute__((ext_vector_type(4))) int   int4v;    // 16B (one ds_read_b128)
typedef __attribute__((ext_vector_type(8))) int   int8v;    // 32B fp8 MFMA A/B frag
typedef __attribute__((ext_vector_type(4))) float floatx4;  // MFMA C/D frag

// ---------------------------------------------------------------- fp32 -> fp8 e4m3 (scaled)
__global__ void cvt_fp8(const float4* __restrict__ src, uint32_t* __restrict__ dst, int n4) {
    int i = blockIdx.x * blockDim.x + threadIdx.x;
    const int stride = gridDim.x * blockDim.x;
    for (; i < n4; i += stride) {
        float4 v = src[i];
        int p = __builtin_amdgcn_cvt_pk_fp8_f32(v.x * SCALE_F, v.y * SCALE_F, 0, 0);
        p = __builtin_amdgcn_cvt_pk_fp8_f32(v.z * SCALE_F, v.w * SCALE_F, p, 1);
        dst[i] = (uint32_t)p;
    }
}

// ---------------------------------------------------------------- GEMM + fused epilogue
__device__ __forceinline__ void load16(const void* g, void* l) {
    __builtin_amdgcn_global_load_lds(
        (const __attribute__((address_space(1))) void*)g,
        (__attribute__((address_space(3))) void*)l, 16, 0, 0);
}

// LDS: DOUBLE-buffered 128x128B fp8 tiles (A,B) = 64 KB. 16B chunk at global
// k-pos q of row R lives at phys pos p = q ^ (R & 7) (frag ds_read_b128s then
// alias only 2-way per quarter-wave = free). Swizzle on the GLOBAL address side
// of global_load_lds (LDS dest must remain wave-base + lane*16B).
//
// K-loop: ONE barrier per tile. At the barrier, this wave's outstanding
// global_load_lds (issued at the previous barrier, a full compute-phase old)
// are drained nearly for free; then next tile's loads are issued immediately
// and the current tile is computed from the other buffer. Buffer parity is
// static (x2 manual unroll); outer loop stays #pragma unroll 1 -- full unroll
// at trip-16 previously ballooned live range to 256 VGPR + scratch spills.
__global__ __launch_bounds__(256) void gemm_lp(
        const char* __restrict__ Af8, const char* __restrict__ Bf8,
        const int* __restrict__ labels, const int* __restrict__ labels_s,
        float* __restrict__ pminp, float* __restrict__ psump) {
    __shared__ __align__(16) char lsA[2][128 * 128];
    __shared__ __align__(16) char lsB[2][128 * 128];
    __shared__ int lab_m[128];
    __shared__ int lab_n[128];

    const int t    = threadIdx.x;
    const int lane = t & 63;
    const int wave = t >> 6;
    const int wm   = wave >> 1;   // row half (0..1)
    const int wn   = wave & 1;    // col half (0..1)
    const int m0   = blockIdx.y * 128;
    const int n0   = blockIdx.x * 128;

    if (t < 128) lab_m[t] = labels[m0 + t];
    else         lab_n[t - 128] = labels_s[n0 + t - 128];

    // staging: issue j (0..3) per matrix; thread t fills phys chunk c = j*256+t.
    // phys row = j*32 + (t>>3), phys pos = t&7  ->  global 16B k-chunk
    // q = (t&7) ^ ((t>>3)&7)   (row&7 = (t>>3)&7, j-independent).
    const int rq = t >> 3;                                  // row within 32-row group
    const int qt = (t & 7) ^ ((t >> 3) & 7);                // swizzled k-chunk
    const char* aPtr = Af8 + (long)(m0 + rq) * K_TOTAL + qt * 16;
    const char* bPtr = Bf8 + (long)(n0 + rq) * K_TOTAL + qt * 16;
    const int ldsOff = wave * 1024;          // wave-uniform LDS base; HW adds lane*16B

    // Fragment bases: row R = (wm|wn)*64 + lcol (+ mi*16), k-chunks {2q,2q+1} at
    // phys (k ^ (lcol&7)). mi-step = +2048 B folds into ds_read immediates.
    const int quad = lane >> 4;
    const int lcol = lane & 15;
    const int plo = ((2 * quad) ^ (lcol & 7)) << 4;
    const int phi = ((2 * quad + 1) ^ (lcol & 7)) << 4;
    const int aRow = (wm * 64 + lcol) * 128;
    const int bRow = (wn * 64 + lcol) * 128;

    floatx4 acc[4][4];
#pragma unroll
    for (int mi = 0; mi < 4; ++mi)
#pragma unroll
        for (int ni = 0; ni < 4; ++ni)
            acc[mi][ni] = (floatx4){0.f, 0.f, 0.f, 0.f};

#define ISSUE_LOADS(tile, p)                                                  \
    do {                                                                      \
        _Pragma("unroll")                                                     \
        for (int j = 0; j < 4; ++j) {                                         \
            load16(aPtr + (tile) * 128 + j * 32 * K_TOTAL, lsA[p] + ldsOff + j * 4096); \
            load16(bPtr + (tile) * 128 + j * 32 * K_TOTAL, lsB[p] + ldsOff + j * 4096); \
        }                                                                     \
    } while (0)

#define COMPUTE(p)                                                            \
    do {                                                                      \
        int8v bv[4];                                                          \
        _Pragma("unroll")                                                     \
        for (int i = 0; i < 4; ++i) {                                         \
            int4v lo = *(const int4v*)(lsB[p] + bRow + i * 2048 + plo);       \
            int4v hi = *(const int4v*)(lsB[p] + bRow + i * 2048 + phi);       \
            bv[i] = (int8v){lo.x, lo.y, lo.z, lo.w, hi.x, hi.y, hi.z, hi.w};  \
        }                                                                     \
        _Pragma("unroll")                                                     \
        for (int mi = 0; mi < 4; ++mi) {                                      \
            int4v lo = *(const int4v*)(lsA[p] + aRow + mi * 2048 + plo);      \
            int4v hi = *(const int4v*)(lsA[p] + aRow + mi * 2048 + phi);      \
            int8v av = (int8v){lo.x, lo.y, lo.z, lo.w, hi.x, hi.y, hi.z, hi.w}; \
            _Pragma("unroll")                                                 \
            for (int ni = 0; ni < 4; ++ni)                                    \
                acc[mi][ni] = __builtin_amdgcn_mfma_scale_f32_16x16x128_f8f6f4( \
                    av, bv[ni], acc[mi][ni], 0, 0,                            \
                    0, SCALE_E8M0, 0, SCALE_E8M0);                            \
        }                                                                     \
    } while (0)

    ISSUE_LOADS(0, 0);                       // prologue: tile 0 -> buf 0

#pragma unroll 1
    for (int kt2 = 0; kt2 < K_TOTAL / 256; ++kt2) {         // 8 x (2 tiles)
        // ---- even tile 2*kt2 in buf 0
        __syncthreads();                     // drains old loads: buf0 ready, buf1 free
        ISSUE_LOADS(1, 1);                   // tile 2*kt2+1 -> buf 1 (always exists)
        COMPUTE(0);
        // ---- odd tile 2*kt2+1 in buf 1
        __syncthreads();                     // buf1 ready, buf0 free
        if (kt2 < K_TOTAL / 256 - 1)
            ISSUE_LOADS(2, 0);               // tile 2*kt2+2 -> buf 0
        COMPUTE(1);
        aPtr += 256;
        bPtr += 256;
    }
#undef ISSUE_LOADS
#undef COMPUTE

    // Epilogue: e = exp(sim/TEMP) = exp2(sim * 28.8539); masked min/sum over cols.
    // C/D layout (shape-determined): col = lane&15, row = quad*4 + reg
    const float scale = 28.853900817779268f;     // 20 * log2(e)
#pragma unroll
    for (int mi = 0; mi < 4; ++mi) {
#pragma unroll
        for (int r = 0; r < 4; ++r) {
            const int row_local = wm * 64 + mi * 16 + quad * 4 + r;
            const int lab = lab_m[row_local];
            float minv = __builtin_inff();
            float sumv = 0.f;
#pragma unroll
            for (int ni = 0; ni < 4; ++ni) {
                const int col_local = wn * 64 + ni * 16 + lcol;
                const float e = exp2f(acc[mi][ni][r] * scale);
                const bool pos = (lab_n[col_local] == lab);
                minv = pos ? fminf(minv, e) : minv;
                sumv = pos ? sumv : (sumv + e);
            }
#pragma unroll
            for (int off = 1; off < 16; off <<= 1) {
                minv = fminf(minv, __shfl_xor(minv, off, 16));
                sumv += __shfl_xor(sumv, off, 16);
            }
            if (lcol == 0) {
                // partials laid out [row][part] so reduce_rows reads coalesced
                const long idx = (long)(m0 + row_local) * NPARTS + blockIdx.x * 2 + wn;
                pminp[idx] = minv;
                psump[idx] = sumv;
            }
        }
    }
}

// ---------------------------------------------------------------- row fold + mean
// one wave per row, 512 blocks x 4 waves = 2048 waves
__global__ __launch_bounds__(256) void reduce_rows(
        const float* __restrict__ pminp, const float* __restrict__ psump,
        float* __restrict__ loss) {
    const int row  = blockIdx.x * 4 + (threadIdx.x >> 6);
    const int lane = threadIdx.x & 63;
    float m = __builtin_inff();
    float s = 0.f;
#pragma unroll
    for (int k = 0; k < NPARTS / 64; ++k) {
        const long j = (long)row * NPARTS + lane + k * 64;
        m = fminf(m, pminp[j]);
        s += psump[j];
    }
#pragma unroll
    for (int off = 1; off < 64; off <<= 1) {
        m = fminf(m, __shfl_xor(m, off, 64));
        s += __shfl_xor(s, off, 64);
    }
    if (lane == 0) loss[row] = -logf(m / (m + s + 1e-6f) + 1e-6f);
}

__global__ void final_mean(const float* __restrict__ loss, float* __restrict__ out) {
    float s = 0.f;
    for (int i = threadIdx.x; i < M_TOTAL; i += 256) s += loss[i];
#pragma unroll
    for (int off = 32; off > 0; off >>= 1) s += __shfl_xor(s, off, 64);
    __shared__ float wsum[4];
    if ((threadIdx.x & 63) == 0) wsum[threadIdx.x >> 6] = s;
    __syncthreads();
    if (threadIdx.x == 0)
        out[0] = (wsum[0] + wsum[1] + wsum[2] + wsum[3]) * (1.0f / (float)M_TOTAL);
}

// ---------------------------------------------------------------- launcher
extern "C" void kernel_launch(void* const* d_in, const int* in_sizes, int n_in,
                              void* d_out, int out_size, void* d_ws, size_t ws_size,
                              hipStream_t stream) {
    const float* feats    = (const float*)d_in[0];
    const float* feats_s  = (const float*)d_in[1];
    const int*   labels   = (const int*)d_in[2];
    const int*   labels_s = (const int*)d_in[3];
    float*       out      = (float*)d_out;

    char* ws = (char*)d_ws;
    char*  Af8   = ws;                                    //  4,194,304 B
    char*  Bf8   = ws + 4194304;                          // 33,554,432 B
    float* pminp = (float*)(ws + 37748736);               //  2,097,152 B
    float* psump = (float*)(ws + 39845888);               //  2,097,152 B
    float* loss  = (float*)(ws + 41943040);               //      8,192 B

    cvt_fp8<<<512,  256, 0, stream>>>((const float4*)feats,   (uint32_t*)Af8,
                                      M_TOTAL * K_TOTAL / 4);
    cvt_fp8<<<2048, 256, 0, stream>>>((const float4*)feats_s, (uint32_t*)Bf8,
                                      N_TOTAL * K_TOTAL / 4);

    dim3 grid(N_TOTAL / 128, M_TOTAL / 128);              // 128 x 16
    gemm_lp<<<grid, 256, 0, stream>>>(Af8, Bf8, labels, labels_s, pminp, psump);

    reduce_rows<<<512, 256, 0, stream>>>(pminp, psump, loss);
    final_mean<<<1, 256, 0, stream>>>(loss, out);
}

// Round 7
// 297.400 us; speedup vs baseline: 1.0332x; 1.0332x over previous
//
#include <hip/hip_runtime.h>
#include <hip/hip_bf16.h>
#include <stdint.h>

// Problem dims (fixed by setup_inputs)
#define M_TOTAL 2048     // B (feats rows)
#define N_TOTAL 16384    // Bs*TOPK (support rows)
#define K_TOTAL 2048     // C
#define NPARTS  256      // 128 n-tiles * 2 n-waves

// Uniform MX scale: stored_fp8 = value * 2^9, HW dequant scale = 2^-9 per operand.
// e8m0 byte = 127 - 9 = 118 = 0x76. Uniform bytes -> immune to scale-lane layout.
#define SCALE_E8M0 0x76767676
#define SCALE_F 512.0f

typedef __attribute__((ext_vector_type(4))) int   int4v;    // 16B (one ds_read_b128)
typedef __attribute__((ext_vector_type(8))) int   int8v;    // 32B fp8 MFMA A/B frag
typedef __attribute__((ext_vector_type(4))) float floatx4;  // MFMA C/D frag

// ---------------------------------------------------------------- fp32 -> fp8 e4m3 (scaled)
__device__ __forceinline__ void cvt_loop(const float4* __restrict__ src,
                                         uint32_t* __restrict__ dst,
                                         int i, int stride, int n4) {
    for (; i < n4; i += stride) {
        float4 v = src[i];
        int p = __builtin_amdgcn_cvt_pk_fp8_f32(v.x * SCALE_F, v.y * SCALE_F, 0, 0);
        p = __builtin_amdgcn_cvt_pk_fp8_f32(v.z * SCALE_F, v.w * SCALE_F, p, 1);
        dst[i] = (uint32_t)p;
    }
}

// one launch for both arrays: blocks [0,512) -> A, [512,2560) -> B (uniform branch)
__global__ void cvt_fp8_all(const float4* __restrict__ a, const float4* __restrict__ b,
                            uint32_t* __restrict__ oa, uint32_t* __restrict__ ob) {
    if (blockIdx.x < 512)
        cvt_loop(a, oa, blockIdx.x * 256 + threadIdx.x, 512 * 256,
                 M_TOTAL * K_TOTAL / 4);
    else
        cvt_loop(b, ob, (blockIdx.x - 512) * 256 + threadIdx.x, 2048 * 256,
                 N_TOTAL * K_TOTAL / 4);
}

// ---------------------------------------------------------------- GEMM + fused epilogue
__device__ __forceinline__ void load16(const void* g, void* l) {
    __builtin_amdgcn_global_load_lds(
        (const __attribute__((address_space(1))) void*)g,
        (__attribute__((address_space(3))) void*)l, 16, 0, 0);
}

// BK=256 single-buffered: LDS = 128 rows x 256 B per matrix (32 KB x2).
// Halves the barrier count vs BK=128 (the vmcnt(0)+barrier drain was ~2/3 of
// K-loop time at MfmaUtil 33%); round-6 measured the 64KB-LDS occupancy cost
// at only ~5%. Two K=128 MFMA steps per staged tile.
//
// Swizzle: 16B chunk at global k-pos q (0..15) of row R lives at phys pos
// p = q ^ (R & 15). Staging (global_load_lds dest = wave-base + lane*16B):
// thread t, issue j: phys row = j*16 + (t>>4), phys pos = t&15 -> global
// k-chunk q = (t&15) ^ (t>>4) (j-independent). Fragment reads: R&15 == lcol,
// step s chunk pair {s*8+2q, s*8+2q+1} at phys (k ^ lcol)*16 -> quarter-wave
// spreads over all 8 bank-groups, 2-way aliasing = free.
//
// K-loop stays #pragma unroll 1: full unroll at const trip count previously
// ballooned live range to 256 VGPR + scratch spills (rounds 3/4).
__global__ __launch_bounds__(256) void gemm_lp(
        const char* __restrict__ Af8, const char* __restrict__ Bf8,
        const int* __restrict__ labels, const int* __restrict__ labels_s,
        float* __restrict__ pminp, float* __restrict__ psump) {
    __shared__ __align__(16) char lsA[128 * 256];
    __shared__ __align__(16) char lsB[128 * 256];
    __shared__ int lab_m[128];
    __shared__ int lab_n[128];

    const int t    = threadIdx.x;
    const int lane = t & 63;
    const int wave = t >> 6;
    const int wm   = wave >> 1;   // row half (0..1)
    const int wn   = wave & 1;    // col half (0..1)
    const int m0   = blockIdx.y * 128;
    const int n0   = blockIdx.x * 128;

    if (t < 128) lab_m[t] = labels[m0 + t];
    else         lab_n[t - 128] = labels_s[n0 + t - 128];

    // staging addressing (see header comment)
    const int rq = t >> 4;                                  // row within 16-row group
    const int qt = (t & 15) ^ (t >> 4);                     // swizzled k-chunk
    const char* aPtr = Af8 + (long)(m0 + rq) * K_TOTAL + qt * 16;
    const char* bPtr = Bf8 + (long)(n0 + rq) * K_TOTAL + qt * 16;
    const int ldsOff = wave * 1024;          // + lane*16B added by HW

    // Fragment bases: row R = (wm|wn)*64 + mi*16 + lcol; mi-step = +4096 B.
    const int quad = lane >> 4;
    const int lcol = lane & 15;
    const int aRow = (wm * 64 + lcol) * 256;
    const int bRow = (wn * 64 + lcol) * 256;
    // per-step swizzled chunk offsets (s=0,1)
    const int lo0 = ((2 * quad)     ^ lcol) << 4;
    const int hi0 = ((2 * quad + 1) ^ lcol) << 4;
    const int lo1 = ((8 + 2 * quad)     ^ lcol) << 4;
    const int hi1 = ((8 + 2 * quad + 1) ^ lcol) << 4;

    floatx4 acc[4][4];
#pragma unroll
    for (int mi = 0; mi < 4; ++mi)
#pragma unroll
        for (int ni = 0; ni < 4; ++ni)
            acc[mi][ni] = (floatx4){0.f, 0.f, 0.f, 0.f};

#define COMPUTE_STEP(plo, phi)                                                \
    do {                                                                      \
        int8v bv[4];                                                          \
        _Pragma("unroll")                                                     \
        for (int i = 0; i < 4; ++i) {                                         \
            int4v lo = *(const int4v*)(lsB + bRow + i * 4096 + (phi ? 0 : 0) + plo); \
            int4v hi = *(const int4v*)(lsB + bRow + i * 4096 + phi);          \
            bv[i] = (int8v){lo.x, lo.y, lo.z, lo.w, hi.x, hi.y, hi.z, hi.w};  \
        }                                                                     \
        _Pragma("unroll")                                                     \
        for (int mi = 0; mi < 4; ++mi) {                                      \
            int4v lo = *(const int4v*)(lsA + aRow + mi * 4096 + plo);         \
            int4v hi = *(const int4v*)(lsA + aRow + mi * 4096 + phi);         \
            int8v av = (int8v){lo.x, lo.y, lo.z, lo.w, hi.x, hi.y, hi.z, hi.w}; \
            _Pragma("unroll")                                                 \
            for (int ni = 0; ni < 4; ++ni)                                    \
                acc[mi][ni] = __builtin_amdgcn_mfma_scale_f32_16x16x128_f8f6f4( \
                    av, bv[ni], acc[mi][ni], 0, 0,                            \
                    0, SCALE_E8M0, 0, SCALE_E8M0);                            \
        }                                                                     \
    } while (0)

#pragma unroll 1
    for (int kt = 0; kt < K_TOTAL / 256; ++kt) {            // 8 iterations, NOT unrolled
        __syncthreads();                         // previous iter's frag reads done
#pragma unroll
        for (int j = 0; j < 8; ++j) {
            load16(aPtr + (long)j * 16 * K_TOTAL, lsA + ldsOff + j * 4096);
            load16(bPtr + (long)j * 16 * K_TOTAL, lsB + ldsOff + j * 4096);
        }
        aPtr += 256;
        bPtr += 256;
        __syncthreads();                         // drains vmcnt -> tiles ready
        COMPUTE_STEP(lo0, hi0);                  // k-block 0 (K=128)
        COMPUTE_STEP(lo1, hi1);                  // k-block 1 (K=128)
    }
#undef COMPUTE_STEP

    // Epilogue: e = exp(sim/TEMP) = exp2(sim * 28.8539); masked min/sum over cols.
    // C/D layout (shape-determined): col = lane&15, row = quad*4 + reg
    const float scale = 28.853900817779268f;     // 20 * log2(e)
#pragma unroll
    for (int mi = 0; mi < 4; ++mi) {
#pragma unroll
        for (int r = 0; r < 4; ++r) {
            const int row_local = wm * 64 + mi * 16 + quad * 4 + r;
            const int lab = lab_m[row_local];
            float minv = __builtin_inff();
            float sumv = 0.f;
#pragma unroll
            for (int ni = 0; ni < 4; ++ni) {
                const int col_local = wn * 64 + ni * 16 + lcol;
                const float e = exp2f(acc[mi][ni][r] * scale);
                const bool pos = (lab_n[col_local] == lab);
                minv = pos ? fminf(minv, e) : minv;
                sumv = pos ? sumv : (sumv + e);
            }
#pragma unroll
            for (int off = 1; off < 16; off <<= 1) {
                minv = fminf(minv, __shfl_xor(minv, off, 16));
                sumv += __shfl_xor(sumv, off, 16);
            }
            if (lcol == 0) {
                // partials laid out [row][part] so reduce_rows reads coalesced
                const long idx = (long)(m0 + row_local) * NPARTS + blockIdx.x * 2 + wn;
                pminp[idx] = minv;
                psump[idx] = sumv;
            }
        }
    }
}

// ---------------------------------------------------------------- row fold + mean
// one wave per row, 512 blocks x 4 waves = 2048 waves
__global__ __launch_bounds__(256) void reduce_rows(
        const float* __restrict__ pminp, const float* __restrict__ psump,
        float* __restrict__ loss) {
    const int row  = blockIdx.x * 4 + (threadIdx.x >> 6);
    const int lane = threadIdx.x & 63;
    float m = __builtin_inff();
    float s = 0.f;
#pragma unroll
    for (int k = 0; k < NPARTS / 64; ++k) {
        const long j = (long)row * NPARTS + lane + k * 64;
        m = fminf(m, pminp[j]);
        s += psump[j];
    }
#pragma unroll
    for (int off = 1; off < 64; off <<= 1) {
        m = fminf(m, __shfl_xor(m, off, 64));
        s += __shfl_xor(s, off, 64);
    }
    if (lane == 0) loss[row] = -logf(m / (m + s + 1e-6f) + 1e-6f);
}

__global__ void final_mean(const float* __restrict__ loss, float* __restrict__ out) {
    float s = 0.f;
    for (int i = threadIdx.x; i < M_TOTAL; i += 256) s += loss[i];
#pragma unroll
    for (int off = 32; off > 0; off >>= 1) s += __shfl_xor(s, off, 64);
    __shared__ float wsum[4];
    if ((threadIdx.x & 63) == 0) wsum[threadIdx.x >> 6] = s;
    __syncthreads();
    if (threadIdx.x == 0)
        out[0] = (wsum[0] + wsum[1] + wsum[2] + wsum[3]) * (1.0f / (float)M_TOTAL);
}

// ---------------------------------------------------------------- launcher
extern "C" void kernel_launch(void* const* d_in, const int* in_sizes, int n_in,
                              void* d_out, int out_size, void* d_ws, size_t ws_size,
                              hipStream_t stream) {
    const float* feats    = (const float*)d_in[0];
    const float* feats_s  = (const float*)d_in[1];
    const int*   labels   = (const int*)d_in[2];
    const int*   labels_s = (const int*)d_in[3];
    float*       out      = (float*)d_out;

    char* ws = (char*)d_ws;
    char*  Af8   = ws;                                    //  4,194,304 B
    char*  Bf8   = ws + 4194304;                          // 33,554,432 B
    float* pminp = (float*)(ws + 37748736);               //  2,097,152 B
    float* psump = (float*)(ws + 39845888);               //  2,097,152 B
    float* loss  = (float*)(ws + 41943040);               //      8,192 B

    cvt_fp8_all<<<2560, 256, 0, stream>>>((const float4*)feats, (const float4*)feats_s,
                                          (uint32_t*)Af8, (uint32_t*)Bf8);

    dim3 grid(N_TOTAL / 128, M_TOTAL / 128);              // 128 x 16
    gemm_lp<<<grid, 256, 0, stream>>>(Af8, Bf8, labels, labels_s, pminp, psump);

    reduce_rows<<<512, 256, 0, stream>>>(pminp, psump, loss);
    final_mean<<<1, 256, 0, stream>>>(loss, out);
}

// Round 8
// 289.086 us; speedup vs baseline: 1.0629x; 1.0288x over previous
//
#include <hip/hip_runtime.h>
#include <hip/hip_bf16.h>
#include <stdint.h>

// Problem dims (fixed by setup_inputs)
#define M_TOTAL 2048     // B (feats rows)
#define N_TOTAL 16384    // Bs*TOPK (support rows)
#define K_TOTAL 2048     // C
#define NPARTS  256      // 128 n-tiles * 2 n-waves

// Uniform MX scale: stored_fp8 = value * 2^9, HW dequant scale = 2^-9 per operand.
// e8m0 byte = 127 - 9 = 118 = 0x76. Uniform bytes -> immune to scale-lane layout.
#define SCALE_E8M0 0x76767676
#define SCALE_F 512.0f

typedef __attribute__((ext_vector_type(4))) int   int4v;    // 16B (one ds_read_b128)
typedef __attribute__((ext_vector_type(8))) int   int8v;    // 32B fp8 MFMA A/B frag
typedef __attribute__((ext_vector_type(4))) float floatx4;  // MFMA C/D frag

// ---------------------------------------------------------------- fp32 -> fp8 e4m3 (scaled)
__device__ __forceinline__ void cvt_loop(const float4* __restrict__ src,
                                         uint32_t* __restrict__ dst,
                                         int i, int stride, int n4) {
    for (; i < n4; i += stride) {
        float4 v = src[i];
        int p = __builtin_amdgcn_cvt_pk_fp8_f32(v.x * SCALE_F, v.y * SCALE_F, 0, 0);
        p = __builtin_amdgcn_cvt_pk_fp8_f32(v.z * SCALE_F, v.w * SCALE_F, p, 1);
        dst[i] = (uint32_t)p;
    }
}

// one launch for both arrays: blocks [0,512) -> A, [512,2560) -> B (uniform branch)
__global__ void cvt_fp8_all(const float4* __restrict__ a, const float4* __restrict__ b,
                            uint32_t* __restrict__ oa, uint32_t* __restrict__ ob) {
    if (blockIdx.x < 512)
        cvt_loop(a, oa, blockIdx.x * 256 + threadIdx.x, 512 * 256,
                 M_TOTAL * K_TOTAL / 4);
    else
        cvt_loop(b, ob, (blockIdx.x - 512) * 256 + threadIdx.x, 2048 * 256,
                 N_TOTAL * K_TOTAL / 4);
}

// ---------------------------------------------------------------- GEMM + fused epilogue
__device__ __forceinline__ void load16(const void* g, void* l) {
    __builtin_amdgcn_global_load_lds(
        (const __attribute__((address_space(1))) void*)g,
        (__attribute__((address_space(3))) void*)l, 16, 0, 0);
}

// ===== Measured-optimum structure (round 5: gemm 88 us, 1560 TF = 96% of the
// m148 MX-fp8 2-barrier plateau). Variants measured and REJECTED:
//   - double-buffer single-barrier (round 6): 105 us — occupancy 25.6->20.5%,
//     implicit multi-wave overlap lost more than the barrier-drain saved.
//   - BK=256 (round 7): 93 us — same occupancy cliff from 64 KB LDS.
//   - full K-loop unroll (rounds 3/4): 256 VGPR + scratch spills, 196 us.
//
// LDS tile: 128 rows x 128 B (K=128 fp8), single-buffered. 16B chunk at global
// k-pos q of row R lives at phys pos p = q ^ (R & 7). Fragment loads are two
// ds_read_b128 per 32B operand; quarter-wave lanes (R&7 = lcol&7) spread over
// all 8 bank-groups -> 2-way aliasing (free per m136; shows as a benign
// ~8.4M SQ_LDS_BANK_CONFLICT count). Swizzle applied on the GLOBAL address
// side of global_load_lds (LDS dest must remain wave-base + lane*16B).
__global__ __launch_bounds__(256) void gemm_lp(
        const char* __restrict__ Af8, const char* __restrict__ Bf8,
        const int* __restrict__ labels, const int* __restrict__ labels_s,
        float* __restrict__ pminp, float* __restrict__ psump) {
    __shared__ __align__(16) char lsA[128 * 128];
    __shared__ __align__(16) char lsB[128 * 128];
    __shared__ int lab_m[128];
    __shared__ int lab_n[128];

    const int t    = threadIdx.x;
    const int lane = t & 63;
    const int wave = t >> 6;
    const int wm   = wave >> 1;   // row half (0..1)
    const int wn   = wave & 1;    // col half (0..1)
    const int m0   = blockIdx.y * 128;
    const int n0   = blockIdx.x * 128;

    if (t < 128) lab_m[t] = labels[m0 + t];
    else         lab_n[t - 128] = labels_s[n0 + t - 128];

    // staging: issue j (0..3) per matrix; thread t fills phys chunk c = j*256+t.
    // phys row = j*32 + (t>>3), phys pos = t&7  ->  global 16B k-chunk
    // q = (t&7) ^ ((t>>3)&7)   (row&7 = (t>>3)&7, j-independent).
    const int rq = t >> 3;                                  // row within 32-row group
    const int qt = (t & 7) ^ ((t >> 3) & 7);                // swizzled k-chunk
    const char* aPtr = Af8 + (long)(m0 + rq) * K_TOTAL + qt * 16;
    const char* bPtr = Bf8 + (long)(n0 + rq) * K_TOTAL + qt * 16;
    char* lA = lsA + wave * 1024;            // wave-uniform LDS base; HW adds lane*16B
    char* lB = lsB + wave * 1024;

    // Fragment bases: row R = (wm|wn)*64 + lcol (+ mi*16), k-chunks {2q,2q+1} at
    // phys (k ^ (lcol&7)). mi-step = +2048 B folds into ds_read immediates.
    const int quad = lane >> 4;
    const int lcol = lane & 15;
    const int plo = ((2 * quad) ^ (lcol & 7)) << 4;
    const int phi = ((2 * quad + 1) ^ (lcol & 7)) << 4;
    const char* aLo = lsA + (wm * 64 + lcol) * 128 + plo;
    const char* aHi = lsA + (wm * 64 + lcol) * 128 + phi;
    const char* bLo = lsB + (wn * 64 + lcol) * 128 + plo;
    const char* bHi = lsB + (wn * 64 + lcol) * 128 + phi;

    floatx4 acc[4][4];
#pragma unroll
    for (int mi = 0; mi < 4; ++mi)
#pragma unroll
        for (int ni = 0; ni < 4; ++ni)
            acc[mi][ni] = (floatx4){0.f, 0.f, 0.f, 0.f};

#pragma unroll 1
    for (int kt = 0; kt < K_TOTAL / 128; ++kt) {            // 16 iterations, NOT unrolled
        __syncthreads();                         // previous iter's frag reads done
#pragma unroll
        for (int j = 0; j < 4; ++j) {
            load16(aPtr + j * 32 * K_TOTAL, lA + j * 4096);
            load16(bPtr + j * 32 * K_TOTAL, lB + j * 4096);
        }
        aPtr += 128;
        bPtr += 128;
        __syncthreads();                         // drains vmcnt -> tiles ready

        // Hold all 4 B-frags (32 VGPRs); stream A-frags one at a time (8 VGPRs).
        int8v bv[4];
#pragma unroll
        for (int i = 0; i < 4; ++i) {
            int4v lo = *(const int4v*)(bLo + i * 2048);
            int4v hi = *(const int4v*)(bHi + i * 2048);
            bv[i] = (int8v){lo.x, lo.y, lo.z, lo.w, hi.x, hi.y, hi.z, hi.w};
        }
#pragma unroll
        for (int mi = 0; mi < 4; ++mi) {
            int4v lo = *(const int4v*)(aLo + mi * 2048);
            int4v hi = *(const int4v*)(aHi + mi * 2048);
            int8v av = (int8v){lo.x, lo.y, lo.z, lo.w, hi.x, hi.y, hi.z, hi.w};
#pragma unroll
            for (int ni = 0; ni < 4; ++ni)
                acc[mi][ni] = __builtin_amdgcn_mfma_scale_f32_16x16x128_f8f6f4(
                    av, bv[ni], acc[mi][ni],
                    0, 0,                         // cbsz=fp8(e4m3), blgp=fp8(e4m3)
                    0, SCALE_E8M0,                // opsel_a, scale_a (2^-9 all bytes)
                    0, SCALE_E8M0);               // opsel_b, scale_b
        }
    }

    // Epilogue: e = exp(sim/TEMP) = exp2(sim * 28.8539); masked min/sum over cols.
    // C/D layout (shape-determined): col = lane&15, row = quad*4 + reg
    const float scale = 28.853900817779268f;     // 20 * log2(e)
#pragma unroll
    for (int mi = 0; mi < 4; ++mi) {
#pragma unroll
        for (int r = 0; r < 4; ++r) {
            const int row_local = wm * 64 + mi * 16 + quad * 4 + r;
            const int lab = lab_m[row_local];
            float minv = __builtin_inff();
            float sumv = 0.f;
#pragma unroll
            for (int ni = 0; ni < 4; ++ni) {
                const int col_local = wn * 64 + ni * 16 + lcol;
                const float e = exp2f(acc[mi][ni][r] * scale);
                const bool pos = (lab_n[col_local] == lab);
                minv = pos ? fminf(minv, e) : minv;
                sumv = pos ? sumv : (sumv + e);
            }
#pragma unroll
            for (int off = 1; off < 16; off <<= 1) {
                minv = fminf(minv, __shfl_xor(minv, off, 16));
                sumv += __shfl_xor(sumv, off, 16);
            }
            if (lcol == 0) {
                // partials laid out [row][part] so reduce_rows reads coalesced
                const long idx = (long)(m0 + row_local) * NPARTS + blockIdx.x * 2 + wn;
                pminp[idx] = minv;
                psump[idx] = sumv;
            }
        }
    }
}

// ---------------------------------------------------------------- row fold + mean
// one wave per row, 512 blocks x 4 waves = 2048 waves
__global__ __launch_bounds__(256) void reduce_rows(
        const float* __restrict__ pminp, const float* __restrict__ psump,
        float* __restrict__ loss) {
    const int row  = blockIdx.x * 4 + (threadIdx.x >> 6);
    const int lane = threadIdx.x & 63;
    float m = __builtin_inff();
    float s = 0.f;
#pragma unroll
    for (int k = 0; k < NPARTS / 64; ++k) {
        const long j = (long)row * NPARTS + lane + k * 64;
        m = fminf(m, pminp[j]);
        s += psump[j];
    }
#pragma unroll
    for (int off = 1; off < 64; off <<= 1) {
        m = fminf(m, __shfl_xor(m, off, 64));
        s += __shfl_xor(s, off, 64);
    }
    if (lane == 0) loss[row] = -logf(m / (m + s + 1e-6f) + 1e-6f);
}

__global__ void final_mean(const float* __restrict__ loss, float* __restrict__ out) {
    float s = 0.f;
    for (int i = threadIdx.x; i < M_TOTAL; i += 256) s += loss[i];
#pragma unroll
    for (int off = 32; off > 0; off >>= 1) s += __shfl_xor(s, off, 64);
    __shared__ float wsum[4];
    if ((threadIdx.x & 63) == 0) wsum[threadIdx.x >> 6] = s;
    __syncthreads();
    if (threadIdx.x == 0)
        out[0] = (wsum[0] + wsum[1] + wsum[2] + wsum[3]) * (1.0f / (float)M_TOTAL);
}

// ---------------------------------------------------------------- launcher
extern "C" void kernel_launch(void* const* d_in, const int* in_sizes, int n_in,
                              void* d_out, int out_size, void* d_ws, size_t ws_size,
                              hipStream_t stream) {
    const float* feats    = (const float*)d_in[0];
    const float* feats_s  = (const float*)d_in[1];
    const int*   labels   = (const int*)d_in[2];
    const int*   labels_s = (const int*)d_in[3];
    float*       out      = (float*)d_out;

    char* ws = (char*)d_ws;
    char*  Af8   = ws;                                    //  4,194,304 B
    char*  Bf8   = ws + 4194304;                          // 33,554,432 B
    float* pminp = (float*)(ws + 37748736);               //  2,097,152 B
    float* psump = (float*)(ws + 39845888);               //  2,097,152 B
    float* loss  = (float*)(ws + 41943040);               //      8,192 B

    cvt_fp8_all<<<2560, 256, 0, stream>>>((const float4*)feats, (const float4*)feats_s,
                                          (uint32_t*)Af8, (uint32_t*)Bf8);

    dim3 grid(N_TOTAL / 128, M_TOTAL / 128);              // 128 x 16
    gemm_lp<<<grid, 256, 0, stream>>>(Af8, Bf8, labels, labels_s, pminp, psump);

    reduce_rows<<<512, 256, 0, stream>>>(pminp, psump, loss);
    final_mean<<<1, 256, 0, stream>>>(loss, out);
}